// Round 3
// baseline (278.040 us; speedup 1.0000x reference)
//
#include <hip/hip_runtime.h>
#include <hip/hip_bf16.h>

#define NB 512
#define NT 256

// Grid barrier: one single-use counter slot per barrier (zeroed by host memset
// each call). Agent-scope atomics on both sides so non-coherent per-XCD L2s
// can't serve stale values. All 512 blocks are guaranteed co-resident:
// 256 CUs x (>=8 blocks/CU capacity at 2KB LDS, <=128 VGPR) >> 512.
__device__ __forceinline__ void gbar(unsigned* cnt) {
    __syncthreads();
    if (threadIdx.x == 0) {
        __threadfence();  // release my plain stores
        __hip_atomic_fetch_add(cnt, 1u, __ATOMIC_ACQ_REL, __HIP_MEMORY_SCOPE_AGENT);
        while (__hip_atomic_load(cnt, __ATOMIC_ACQUIRE, __HIP_MEMORY_SCOPE_AGENT) < NB) {
            __builtin_amdgcn_s_sleep(2);
        }
        __threadfence();  // acquire before reading others' data
    }
    __syncthreads();
}

__device__ __forceinline__ float aload(const float* p) {
    return __hip_atomic_load(p, __ATOMIC_RELAXED, __HIP_MEMORY_SCOPE_AGENT);
}

// Phases:
//  P0: zero deg[N], s[N] (agent-scope stores)        -- bar0
//  P1: deg[dst] += 1 (int4 edge loads, fp32 atomics) -- bar1
//  P2: s[dst] += x[src]*rsqrt(deg[src]+1)            -- bar2
//  P3: per-graph pool + MLP chain
__global__ __launch_bounds__(NT, 4)
void gnn_fused(const float* __restrict__ x, const float* __restrict__ y,
               const int* __restrict__ src, const int* __restrict__ dst,
               const float* __restrict__ gcn_w, const float* __restrict__ gcn_b,
               const float* __restrict__ w2, const float* __restrict__ b2,
               const float* __restrict__ w3, const float* __restrict__ b3,
               const float* __restrict__ w4, const float* __restrict__ b4,
               float* __restrict__ out,
               float* __restrict__ deg, float* __restrict__ s,
               unsigned* __restrict__ bar,
               int N, int E, int B, int npg)
{
    const int g = blockIdx.x * NT + threadIdx.x;
    const int G = NB * NT;
    const int tid = threadIdx.x;

    // ---- P0: zero accumulators (deg and s contiguous) ----
    for (int i = g; i < 2 * N; i += G)
        __hip_atomic_store(&deg[i], 0.0f, __ATOMIC_RELAXED, __HIP_MEMORY_SCOPE_AGENT);
    gbar(&bar[0]);

    // ---- P1: degree count ----
    const int E4 = E >> 2;
    const int4* dst4 = reinterpret_cast<const int4*>(dst);
    for (int v = g; v < E4; v += G) {
        int4 d = dst4[v];
        atomicAdd(&deg[d.x], 1.0f);
        atomicAdd(&deg[d.y], 1.0f);
        atomicAdd(&deg[d.z], 1.0f);
        atomicAdd(&deg[d.w], 1.0f);
    }
    for (int e = (E4 << 2) + g; e < E; e += G)
        atomicAdd(&deg[dst[e]], 1.0f);
    gbar(&bar[1]);

    // ---- P2: message scatter (per-edge rsqrt; deg read agent-scope) ----
    const int4* src4 = reinterpret_cast<const int4*>(src);
    for (int v = g; v < E4; v += G) {
        int4 a = src4[v];
        int4 b = dst4[v];
        float vx = x[a.x] * rsqrtf(aload(&deg[a.x]) + 1.0f);
        float vy = x[a.y] * rsqrtf(aload(&deg[a.y]) + 1.0f);
        float vz = x[a.z] * rsqrtf(aload(&deg[a.z]) + 1.0f);
        float vw = x[a.w] * rsqrtf(aload(&deg[a.w]) + 1.0f);
        atomicAdd(&s[b.x], vx);
        atomicAdd(&s[b.y], vy);
        atomicAdd(&s[b.z], vz);
        atomicAdd(&s[b.w], vw);
    }
    for (int e = (E4 << 2) + g; e < E; e += G) {
        int a = src[e];
        atomicAdd(&s[dst[e]], x[a] * rsqrtf(aload(&deg[a]) + 1.0f));
    }
    gbar(&bar[2]);

    // ---- P3: per-graph pool + MLP (block handles graphs blockIdx, +NB, ...) ----
    __shared__ float t_lds[128];
    __shared__ float pooled[128];
    __shared__ float concat[65];
    __shared__ float hfc[32];

    for (int b = blockIdx.x; b < B; b += NB) {
        if (tid < npg) {
            int n = b * npg + tid;
            float dv = aload(&deg[n]);
            float sv = aload(&s[n]);
            float di = rsqrtf(dv + 1.0f);
            t_lds[tid] = di * sv + x[n] * di * di;
        }
        __syncthreads();

        if (tid < 128) {
            float gw = gcn_w[tid];
            float gb = gcn_b[tid];
            float sum = 0.0f;
            for (int i = 0; i < npg; ++i)
                sum += fmaxf(t_lds[i] * gw + gb, 0.0f);
            pooled[tid] = sum * (1.0f / (float)npg);
        }
        __syncthreads();

        if (tid < 64) {
            float dot = b2[tid];
            for (int k = 0; k < 128; ++k)
                dot += pooled[k] * w2[k * 64 + tid];
            concat[tid] = fmaxf(dot, 0.0f);
        }
        if (tid == 64) concat[64] = y[b];
        __syncthreads();

        if (tid < 32) {
            float dot = b3[tid];
            for (int i = 0; i < 65; ++i)
                dot += concat[i] * w3[i * 32 + tid];
            hfc[tid] = fmaxf(dot, 0.0f);
        }
        __syncthreads();

        if (tid == 0) {
            float dot = b4[0];
            for (int j = 0; j < 32; ++j)
                dot += hfc[j] * w4[j];
            out[b] = dot;
        }
        __syncthreads();  // protect t_lds/pooled before next graph iteration
    }
}

extern "C" void kernel_launch(void* const* d_in, const int* in_sizes, int n_in,
                              void* d_out, int out_size, void* d_ws, size_t ws_size,
                              hipStream_t stream) {
    const float* x     = (const float*)d_in[0];
    const float* y     = (const float*)d_in[1];
    const int*   ei    = (const int*)d_in[2];
    // d_in[3] = batch (unused: batch[n] == n / (N/B) by construction)
    const float* gcn_w = (const float*)d_in[4];
    const float* gcn_b = (const float*)d_in[5];
    const float* w2    = (const float*)d_in[6];
    const float* b2    = (const float*)d_in[7];
    const float* w3    = (const float*)d_in[8];
    const float* b3    = (const float*)d_in[9];
    const float* w4    = (const float*)d_in[10];
    const float* b4    = (const float*)d_in[11];
    float* out = (float*)d_out;

    const int N = in_sizes[0];      // 100000
    const int B = in_sizes[1];      // 1000
    const int E = in_sizes[2] / 2;  // 600000
    const int npg = N / B;          // 100

    const int* src = ei;
    const int* dst = ei + E;

    unsigned* bar = (unsigned*)d_ws;                       // 3 barrier slots (64B reserved)
    float* deg = (float*)((char*)d_ws + 64);               // [N]
    float* s   = deg + N;                                  // [N] contiguous with deg

    hipMemsetAsync(d_ws, 0, 64, stream);  // zero barrier slots only; deg/s zeroed in-kernel

    gnn_fused<<<dim3(NB), dim3(NT), 0, stream>>>(
        x, y, src, dst, gcn_w, gcn_b, w2, b2, w3, b3, w4, b4,
        out, deg, s, bar, N, E, B, npg);
}

// Round 4
// 82.560 us; speedup vs baseline: 3.3677x; 3.3677x over previous
//
#include <hip/hip_runtime.h>
#include <hip/hip_bf16.h>

// P1: deg[n] = #edges with dst==n. int4 edge loads, fire-and-forget fp32 atomics.
__global__ void deg_kernel(const int* __restrict__ dst, float* __restrict__ deg, int E) {
    int v = blockIdx.x * blockDim.x + threadIdx.x;
    const int E4 = E >> 2;
    if (v < E4) {
        int4 d = reinterpret_cast<const int4*>(dst)[v];
        atomicAdd(&deg[d.x], 1.0f);
        atomicAdd(&deg[d.y], 1.0f);
        atomicAdd(&deg[d.z], 1.0f);
        atomicAdd(&deg[d.w], 1.0f);
    }
    // tail (E % 4 != 0)
    int e = (E4 << 2) + v;
    if (v < (E & 3) && e < E) atomicAdd(&deg[dst[e]], 1.0f);
}

// P2: s[dst] += x[src] * rsqrt(deg[src]+1). x/deg are 400 KB tables -> L2-resident gathers.
__global__ void edge_kernel(const int* __restrict__ src, const int* __restrict__ dst,
                            const float* __restrict__ x, const float* __restrict__ deg,
                            float* __restrict__ s, int E) {
    int v = blockIdx.x * blockDim.x + threadIdx.x;
    const int E4 = E >> 2;
    if (v < E4) {
        int4 a = reinterpret_cast<const int4*>(src)[v];
        int4 b = reinterpret_cast<const int4*>(dst)[v];
        float vx = x[a.x] * rsqrtf(deg[a.x] + 1.0f);
        float vy = x[a.y] * rsqrtf(deg[a.y] + 1.0f);
        float vz = x[a.z] * rsqrtf(deg[a.z] + 1.0f);
        float vw = x[a.w] * rsqrtf(deg[a.w] + 1.0f);
        atomicAdd(&s[b.x], vx);
        atomicAdd(&s[b.y], vy);
        atomicAdd(&s[b.z], vz);
        atomicAdd(&s[b.w], vw);
    }
    int e = (E4 << 2) + v;
    if (v < (E & 3) && e < E) {
        int a = src[e];
        atomicAdd(&s[dst[e]], x[a] * rsqrtf(deg[a] + 1.0f));
    }
}

// P3: one block per graph (128 threads). t = dinv*s + x*dinv^2; pooled = mean relu(t*gw+gb);
// then 128->64 relu, concat y, 65->32 relu, 32->1.
__global__ void pool_mlp_kernel(const float* __restrict__ x, const float* __restrict__ y,
                                const float* __restrict__ deg, const float* __restrict__ s,
                                const float* __restrict__ gcn_w, const float* __restrict__ gcn_b,
                                const float* __restrict__ w2, const float* __restrict__ b2,
                                const float* __restrict__ w3, const float* __restrict__ b3,
                                const float* __restrict__ w4, const float* __restrict__ b4,
                                float* __restrict__ out, int npg) {
    const int b = blockIdx.x;
    const int tid = threadIdx.x;  // 0..127

    __shared__ float t_lds[128];
    __shared__ float pooled[128];
    __shared__ float concat[65];
    __shared__ float hfc[32];

    if (tid < npg) {
        int n = b * npg + tid;
        float di = rsqrtf(deg[n] + 1.0f);
        t_lds[tid] = di * s[n] + x[n] * di * di;
    }
    __syncthreads();

    {
        float gw = gcn_w[tid];
        float gb = gcn_b[tid];
        float sum = 0.0f;
        for (int i = 0; i < npg; ++i)
            sum += fmaxf(t_lds[i] * gw + gb, 0.0f);
        pooled[tid] = sum * (1.0f / (float)npg);
    }
    __syncthreads();

    if (tid < 64) {
        float dot = b2[tid];
        for (int k = 0; k < 128; ++k)
            dot += pooled[k] * w2[k * 64 + tid];
        concat[tid] = fmaxf(dot, 0.0f);
    }
    if (tid == 64) concat[64] = y[b];
    __syncthreads();

    if (tid < 32) {
        float dot = b3[tid];
        for (int i = 0; i < 65; ++i)
            dot += concat[i] * w3[i * 32 + tid];
        hfc[tid] = fmaxf(dot, 0.0f);
    }
    __syncthreads();

    if (tid == 0) {
        float dot = b4[0];
        for (int j = 0; j < 32; ++j)
            dot += hfc[j] * w4[j];
        out[b] = dot;
    }
}

extern "C" void kernel_launch(void* const* d_in, const int* in_sizes, int n_in,
                              void* d_out, int out_size, void* d_ws, size_t ws_size,
                              hipStream_t stream) {
    const float* x     = (const float*)d_in[0];
    const float* y     = (const float*)d_in[1];
    const int*   ei    = (const int*)d_in[2];
    // d_in[3] = batch (unused: batch[n] == n / (N/B) by construction)
    const float* gcn_w = (const float*)d_in[4];
    const float* gcn_b = (const float*)d_in[5];
    const float* w2    = (const float*)d_in[6];
    const float* b2    = (const float*)d_in[7];
    const float* w3    = (const float*)d_in[8];
    const float* b3    = (const float*)d_in[9];
    const float* w4    = (const float*)d_in[10];
    const float* b4    = (const float*)d_in[11];
    float* out = (float*)d_out;

    const int N = in_sizes[0];      // 100000
    const int B = in_sizes[1];      // 1000
    const int E = in_sizes[2] / 2;  // 600000
    const int npg = N / B;          // 100

    const int* src = ei;
    const int* dst = ei + E;

    float* deg = (float*)d_ws;      // [N]
    float* s   = deg + N;           // [N] contiguous

    hipMemsetAsync(d_ws, 0, (size_t)2 * N * sizeof(float), stream);

    const int E4 = E >> 2;
    const int nthr = E4 + 4;                 // int4 body + <=4 tail lanes
    const int nblk = (nthr + 255) / 256;
    deg_kernel<<<nblk, 256, 0, stream>>>(dst, deg, E);
    edge_kernel<<<nblk, 256, 0, stream>>>(src, dst, x, deg, s, E);
    pool_mlp_kernel<<<B, 128, 0, stream>>>(x, y, deg, s, gcn_w, gcn_b,
                                           w2, b2, w3, b3, w4, b4, out, npg);
}